// Round 7
// baseline (241.015 us; speedup 1.0000x reference)
//
#include <hip/hip_runtime.h>
#include <hip/hip_bf16.h>
#include <math.h>

// GQA forward, round 7: round 6 + the missing cross-lane l-reduction.
//  BUG FIX: in the 32x32 C/D layout each lane holds only HALF its q-column's
//  keys (row = (r&3)+8*(r>>2)+4*l5); round 6 dropped the partner-lane merge
//  of the softmax denominator -> O/l blew up (absmax 807). Fixed-max l is a
//  plain sum, so ONE `lrow += shfl_xor(lrow,32)` after the k-loop suffices.

#define N_SEQ 2048
#define EMB   1024
#define NH    16
#define NKV   4
#define HD    64
#define BATCH 2
#define M_TOT 4096
#define QKV_N 1536

typedef __attribute__((ext_vector_type(8)))  short short8;   // 8 bf16
typedef __attribute__((ext_vector_type(4)))  float f32x4;
typedef __attribute__((ext_vector_type(16))) float f32x16;

__device__ __forceinline__ ushort f2bf(float f) {
    union { __hip_bfloat16 h; ushort u; } cv;
    cv.h = __float2bfloat16(f);
    return cv.u;
}
__device__ __forceinline__ float bf2f(ushort u) {
    union { __hip_bfloat16 h; ushort u; } cv;
    cv.u = u;
    return __bfloat162float(cv.h);
}
__device__ __forceinline__ uint pack2bf(float a, float b) {
    union { __hip_bfloat162 h; uint u; } cv;
    cv.h = __float22bfloat162_rn(float2{a, b});
    return cv.u;
}

// ---------------------------------------------------------------------------
// Fused prep (unchanged)
// ---------------------------------------------------------------------------
__device__ __forceinline__ void cvt4(const float* __restrict__ s,
                                     ushort* __restrict__ d, long g, long gd) {
    const float4 v = ((const float4*)s)[g];
    ushort4 o;
    o.x = f2bf(v.x); o.y = f2bf(v.y); o.z = f2bf(v.z); o.w = f2bf(v.w);
    ((ushort4*)d)[gd] = o;
}

__global__ __launch_bounds__(256) void prep_kernel(
    const float* __restrict__ x,  const float* __restrict__ wq,
    const float* __restrict__ wk, const float* __restrict__ wv,
    const float* __restrict__ wp, const float* __restrict__ bq,
    const float* __restrict__ bk, const float* __restrict__ bv,
    ushort* __restrict__ xb, ushort* __restrict__ Wqkv,
    ushort* __restrict__ Wproj, float* __restrict__ bqkv)
{
    const long i = (long)blockIdx.x * 256 + threadIdx.x;
    if (i < 1048576) {
        cvt4(x, xb, i, i);
    } else if (i < 1310720) {
        const long g = i - 1048576;
        cvt4(wq, Wqkv, g, g);
    } else if (i < 1376256) {
        const long g = i - 1310720;
        cvt4(wk, Wqkv, g, 262144 + g);
    } else if (i < 1441792) {
        const long g = i - 1376256;
        cvt4(wv, Wqkv, g, 327680 + g);
    } else if (i < 1703936) {
        const long g = i - 1441792;
        cvt4(wp, Wproj, g, g);
    } else if (i < 1704320) {
        const long j = i - 1703936;
        float4 v;
        if (j < 256)      v = ((const float4*)bq)[j];
        else if (j < 320) v = ((const float4*)bk)[j - 256];
        else              v = ((const float4*)bv)[j - 320];
        ((float4*)bqkv)[j] = v;
    }
}

// ---------------------------------------------------------------------------
// bf16 MFMA GEMM, 64(M)x128(N) tile, BK=32, 4 waves (wave = 32m x 64n).
// ---------------------------------------------------------------------------
template <bool BF16OUT>
__global__ __launch_bounds__(256) void gemm_mfma_kernel(
    const ushort* __restrict__ A, const ushort* __restrict__ W,
    const float* __restrict__ bias, void* __restrict__ Cout,
    int K, int ldc)
{
    __shared__ ushort As[64 * 40];
    __shared__ ushort Bs[128 * 40];

    const int tid = threadIdx.x;
    const int m0 = blockIdx.y * 64, n0 = blockIdx.x * 128;
    const int w = tid >> 6, lane = tid & 63;
    const int quad = lane >> 4, l16 = lane & 15;
    const int wm = (w & 1) * 32, wn = (w >> 1) * 64;

    f32x4 acc[2][4] = {};

    float bb[4];
#pragma unroll
    for (int j = 0; j < 4; ++j) bb[j] = bias[n0 + wn + j * 16 + l16];

    const int r0 = tid >> 2;
    const int c0 = tid & 3;
    const ushort* Ap = A + (size_t)(m0 + r0) * K + c0 * 8;
    const ushort* Wp = W + (size_t)(n0 + r0) * K + c0 * 8;

    for (int k0 = 0; k0 < K; k0 += 32) {
        const short8 a0 = *(const short8*)(Ap + k0);
        const short8 b0 = *(const short8*)(Wp + k0);
        const short8 b1 = *(const short8*)(Wp + (size_t)64 * K + k0);
        __syncthreads();
        *(short8*)&As[r0 * 40 + c0 * 8] = a0;
        *(short8*)&Bs[r0 * 40 + c0 * 8] = b0;
        *(short8*)&Bs[(r0 + 64) * 40 + c0 * 8] = b1;
        __syncthreads();

        short8 aF[2], bF[4];
#pragma unroll
        for (int i = 0; i < 2; ++i)
            aF[i] = *(const short8*)&As[(wm + i * 16 + l16) * 40 + quad * 8];
#pragma unroll
        for (int j = 0; j < 4; ++j)
            bF[j] = *(const short8*)&Bs[(wn + j * 16 + l16) * 40 + quad * 8];
#pragma unroll
        for (int i = 0; i < 2; ++i)
#pragma unroll
            for (int j = 0; j < 4; ++j)
                acc[i][j] = __builtin_amdgcn_mfma_f32_16x16x32_bf16(
                    aF[i], bF[j], acc[i][j], 0, 0, 0);
    }

#pragma unroll
    for (int i = 0; i < 2; ++i) {
        const int rowb = m0 + wm + i * 16 + quad * 4;
#pragma unroll
        for (int j = 0; j < 4; ++j) {
            const int col = n0 + wn + j * 16 + l16;
#pragma unroll
            for (int r = 0; r < 4; ++r) {
                const float vv = acc[i][j][r] + bb[j];
                if (BF16OUT)
                    ((ushort*)Cout)[(size_t)(rowb + r) * ldc + col] = f2bf(vv);
                else
                    ((float*)Cout)[(size_t)(rowb + r) * ldc + col] = vv;
            }
        }
    }
}

// ---------------------------------------------------------------------------
// Fused RMSNorm+RoPE (Q,K) + V transpose, one launch (unchanged from r6).
// ---------------------------------------------------------------------------
__global__ __launch_bounds__(256) void norm_rope_tv_kernel(
    const ushort* __restrict__ Tq, const float* __restrict__ qn_w,
    const float* __restrict__ kn_w, const float* __restrict__ sinp,
    const float* __restrict__ cosp, ushort* __restrict__ Qb,
    ushort* __restrict__ Kf, ushort* __restrict__ Vf)
{
    __shared__ ushort L[64 * 72];
    const int tid = threadIdx.x;

    if (blockIdx.x < 20480) {
        const int gw = (int)(((long)blockIdx.x * 256 + tid) >> 6);
        const int lane = tid & 63;

        const bool isQ = (gw < 65536);
        const int vec = isQ ? gw : gw - 65536;
        const int hshift = isQ ? 4 : 2;
        const int colBase = isQ ? 0 : EMB;
        const float* nw = isQ ? qn_w : kn_w;
        const float outScale = isQ ? 0.125f * 1.44269504f : 1.0f;

        const int m = vec >> hshift;
        const int h = vec & ((1 << hshift) - 1);
        const int n = m & (N_SEQ - 1);
        const int b = m >> 11;

        const float t = bf2f(Tq[(size_t)m * QKV_N + colBase + h * HD + lane]);
        float s = t * t;
#pragma unroll
        for (int mask = 32; mask; mask >>= 1) s += __shfl_xor(s, mask, 64);
        const float r = rsqrtf(s * (1.0f / 64.0f) + 1e-6f);

        const float tn = t * r * nw[lane];
        const float partner = __shfl_xor(tn, 32, 64);
        const float rot = (lane < 32) ? -partner : partner;
        const float val = (tn * cosp[n * HD + lane] + rot * sinp[n * HD + lane]) * outScale;

        if (isQ) {
            Qb[((size_t)((b << 4) + h) * N_SEQ + n) * HD + lane] = f2bf(val);
        } else {
            const int kt = n >> 6, rr = n & 63, ss = rr >> 5, l32k = rr & 31;
            const int c = lane >> 4, l5k = (lane >> 3) & 1, j = lane & 7;
            Kf[((size_t)(b * NKV + h) * 32 + kt) * 4096
               + (ss * 4 + c) * 512 + l32k * 16 + l5k * 8 + j] = f2bf(val);
        }
        return;
    }

    // ---- V transpose path ----
    const int bid = blockIdx.x - 20480;    // 0..255
    const int kt = bid & 31;
    const int bkv = bid >> 5;
    const int n0 = kt * 64;
    const int b = bkv >> 2, kv = bkv & 3;

#pragma unroll
    for (int it = 0; it < 2; ++it) {
        const int j = tid + it * 256;
        const int r = j >> 3, c = j & 7;
        const short8 v = *(const short8*)&Tq[(size_t)(b * N_SEQ + n0 + r) * QKV_N
                                             + 1280 + kv * HD + c * 8];
        *(short8*)&L[r * 72 + c * 8] = v;
    }
    __syncthreads();
#pragma unroll
    for (int it = 0; it < 2; ++it) {
        const int j = tid + it * 256;
        const int d = j >> 3, c8 = j & 7;
        short8 o;
#pragma unroll
        for (int e = 0; e < 8; ++e) o[e] = (short)L[(c8 * 8 + e) * 72 + d];
        const int ss = c8 >> 2, tt = (c8 >> 1) & 1, l5v = c8 & 1;
        const int d2 = d >> 5, l32v = d & 31;
        *(short8*)&Vf[((size_t)bkv * 32 + kt) * 4096
                      + ((ss * 2 + tt) * 2 + d2) * 512 + l32v * 16 + l5v * 8] = o;
    }
}

// ---------------------------------------------------------------------------
// Barrier-free flash, fixed-max softmax (with the cross-lane l fix).
// ---------------------------------------------------------------------------
__global__ __launch_bounds__(256, 4) void flash_mfma32_kernel(
    const ushort* __restrict__ Qb, const ushort* __restrict__ Kf,
    const ushort* __restrict__ Vf, ushort* __restrict__ Ob)
{
    __shared__ float fsm[4352];

    const int qt = blockIdx.x;
    const int bh = blockIdx.y;
    const int b = bh >> 4, h = bh & 15;
    const int kvh = h >> 2;
    const int tid = threadIdx.x;
    const int w = tid >> 6, lane = tid & 63;
    const int l32 = lane & 31, l5 = lane >> 5;
    const int qg = w & 1;
    const int kh = w >> 1;

    const ushort* Qg = Qb + ((size_t)bh * N_SEQ + qt * 64 + qg * 32) * HD;
    const size_t kvbase = (size_t)(b * NKV + kvh) * (32 * 4096);
    const ushort* Kp = Kf + kvbase + (size_t)kh * 16 * 4096;
    const ushort* Vp = Vf + kvbase + (size_t)kh * 16 * 4096;
    const int loff = l32 * 16 + l5 * 8;

    short8 qF[4];
#pragma unroll
    for (int c = 0; c < 4; ++c)
        qF[c] = *(const short8*)&Qg[(size_t)l32 * HD + c * 16 + l5 * 8];

    f32x16 Oa[2] = {};
    float lrow = 0.0f;

    short8 kN[2][4];
#pragma unroll
    for (int s = 0; s < 2; ++s)
#pragma unroll
        for (int c = 0; c < 4; ++c)
            kN[s][c] = *(const short8*)&Kp[(s * 4 + c) * 512 + loff];

    for (int i = 0; i < 16; ++i) {
        short8 kC[2][4];
#pragma unroll
        for (int s = 0; s < 2; ++s)
#pragma unroll
            for (int c = 0; c < 4; ++c) kC[s][c] = kN[s][c];

        const ushort* Vt = Vp + i * 4096;
        short8 vT[2][2][2];
#pragma unroll
        for (int s = 0; s < 2; ++s)
#pragma unroll
            for (int t = 0; t < 2; ++t)
#pragma unroll
                for (int d2 = 0; d2 < 2; ++d2)
                    vT[s][t][d2] = *(const short8*)&Vt[((s * 2 + t) * 2 + d2) * 512 + loff];

        if (i + 1 < 16) {
            const ushort* Kt = Kp + (i + 1) * 4096;
#pragma unroll
            for (int s = 0; s < 2; ++s)
#pragma unroll
                for (int c = 0; c < 4; ++c)
                    kN[s][c] = *(const short8*)&Kt[(s * 4 + c) * 512 + loff];
        }

        f32x16 Sv[2] = {};
#pragma unroll
        for (int s = 0; s < 2; ++s)
#pragma unroll
            for (int c = 0; c < 4; ++c)
                Sv[s] = __builtin_amdgcn_mfma_f32_32x32x16_bf16(kC[s][c], qF[c], Sv[s], 0, 0, 0);

        // P = exp2(S'); l += sum of THIS lane's 32 key-entries
        // (partner lane's key-half merged once after the loop)
        float rs = 0.0f;
#pragma unroll
        for (int s = 0; s < 2; ++s)
#pragma unroll
            for (int r = 0; r < 16; ++r) {
                Sv[s][r] = __builtin_amdgcn_exp2f(Sv[s][r]);
                rs += Sv[s][r];
            }
        lrow += rs;

        uint P2[2][8];
#pragma unroll
        for (int s = 0; s < 2; ++s)
#pragma unroll
            for (int g = 0; g < 4; ++g)
#pragma unroll
                for (int hh = 0; hh < 2; ++hh)
                    P2[s][g * 2 + hh] =
                        pack2bf(Sv[s][4 * g + 2 * hh], Sv[s][4 * g + 2 * hh + 1]);

#pragma unroll
        for (int s = 0; s < 2; ++s)
#pragma unroll
            for (int t = 0; t < 2; ++t) {
                const uint snd0 = l5 ? P2[s][4 * t + 0] : P2[s][4 * t + 2];
                const uint snd1 = l5 ? P2[s][4 * t + 1] : P2[s][4 * t + 3];
                const uint kp0  = l5 ? P2[s][4 * t + 2] : P2[s][4 * t + 0];
                const uint kp1  = l5 ? P2[s][4 * t + 3] : P2[s][4 * t + 1];
                const uint rcv0 = __shfl_xor(snd0, 32, 64);
                const uint rcv1 = __shfl_xor(snd1, 32, 64);
                union { uint u[4]; short8 s8; } pb;
                pb.u[0] = l5 ? rcv0 : kp0;
                pb.u[1] = l5 ? rcv1 : kp1;
                pb.u[2] = l5 ? kp0 : rcv0;
                pb.u[3] = l5 ? kp1 : rcv1;
#pragma unroll
                for (int d2 = 0; d2 < 2; ++d2)
                    Oa[d2] = __builtin_amdgcn_mfma_f32_32x32x16_bf16(
                        vT[s][t][d2], pb.s8, Oa[d2], 0, 0, 0);
            }
    }

    // FIX: fold in the partner lane's key-half of the denominator.
    lrow += __shfl_xor(lrow, 32, 64);

    // ---- merge k-halves: plain sums ----
    float* buf = fsm + qg * 2112;
    if (kh == 1) {
#pragma unroll
        for (int d2 = 0; d2 < 2; ++d2)
#pragma unroll
            for (int r = 0; r < 16; ++r)
                buf[(d2 * 16 + r) * 64 + lane] = Oa[d2][r];
        buf[2048 + lane] = lrow;
    }
    __syncthreads();

    if (kh == 0) {
        lrow += buf[2048 + lane];
#pragma unroll
        for (int d2 = 0; d2 < 2; ++d2)
#pragma unroll
            for (int r = 0; r < 16; ++r)
                Oa[d2][r] += buf[(d2 * 16 + r) * 64 + lane];
    }
    __syncthreads();

    // ---- epilogue: normalize + transpose via LDS, coalesced store ----
    ushort* Os = (ushort*)fsm;
    if (kh == 0) {
        const float inv = 1.0f / lrow;
#pragma unroll
        for (int d2 = 0; d2 < 2; ++d2)
#pragma unroll
            for (int r = 0; r < 16; ++r) {
                const int d = d2 * 32 + (r & 3) + 8 * (r >> 2) + 4 * l5;
                Os[(qg * 32 + l32) * 68 + d] = f2bf(Oa[d2][r] * inv);
            }
    }
    __syncthreads();

    const int row = tid >> 2, cc = (tid & 3) * 16;
#pragma unroll
    for (int i = 0; i < 2; ++i) {
        const short8 v = *(const short8*)&Os[row * 68 + cc + i * 8];
        *(short8*)&Ob[((size_t)b * N_SEQ + qt * 64 + row) * EMB + h * HD + cc + i * 8] = v;
    }
}

// ---------------------------------------------------------------------------
extern "C" void kernel_launch(void* const* d_in, const int* in_sizes, int n_in,
                              void* d_out, int out_size, void* d_ws, size_t ws_size,
                              hipStream_t stream)
{
    const float* x      = (const float*)d_in[0];
    const float* sinp   = (const float*)d_in[1];
    const float* cosp   = (const float*)d_in[2];
    const float* wq_w   = (const float*)d_in[3];
    const float* wq_b   = (const float*)d_in[4];
    const float* wk_w   = (const float*)d_in[5];
    const float* wk_b   = (const float*)d_in[6];
    const float* wv_w   = (const float*)d_in[7];
    const float* wv_b   = (const float*)d_in[8];
    const float* qn_w   = (const float*)d_in[9];
    const float* kn_w   = (const float*)d_in[10];
    const float* proj_w = (const float*)d_in[11];
    const float* proj_b = (const float*)d_in[12];
    float* out = (float*)d_out;

    // workspace layout (ushort elements) — ~39 MB
    ushort* Tq    = (ushort*)d_ws;            // 4096*1536
    ushort* xb    = Tq + 6291456;             // 4096*1024 (reused as Ob)
    ushort* Wqkv  = xb + 4194304;             // 1536*1024
    ushort* Wproj = Wqkv + 1572864;           // 1024*1024
    float*  bqkv  = (float*)(Wproj + 1048576);// 1536
    ushort* Qb    = (ushort*)(bqkv + 1536);   // 2*16*2048*64
    ushort* Kf    = Qb + 4194304;             // frag-order K
    ushort* Vf    = Kf + 1048576;             // frag-order V^T

    prep_kernel<<<6658, 256, 0, stream>>>(x, wq_w, wk_w, wv_w, proj_w,
                                          wq_b, wk_b, wv_b,
                                          xb, Wqkv, Wproj, bqkv);

    gemm_mfma_kernel<true><<<dim3(QKV_N / 128, M_TOT / 64), 256, 0, stream>>>(
        xb, Wqkv, bqkv, Tq, EMB, QKV_N);

    norm_rope_tv_kernel<<<20736, 256, 0, stream>>>(Tq, qn_w, kn_w, sinp, cosp,
                                                   Qb, Kf, Vf);

    flash_mfma32_kernel<<<dim3(32, 32), 256, 0, stream>>>(Qb, Kf, Vf, xb);

    gemm_mfma_kernel<false><<<dim3(EMB / 128, M_TOT / 64), 256, 0, stream>>>(
        xb, Wproj, proj_b, out, EMB, EMB);
}

// Round 8
// 228.450 us; speedup vs baseline: 1.0550x; 1.0550x over previous
//
#include <hip/hip_runtime.h>
#include <hip/hip_bf16.h>
#include <math.h>

// GQA forward, round 8: round 7 + XCD-pinned flash grid.
//  Flash grid flattened to 1-D 1024 blocks with bh = (blk&7) + 8*((blk>>3)>>5),
//  qt = (blk>>3)&31. Under round-robin block->XCD dispatch, each XCD touches
//  only 4 bh values -> K/V working set 2 MB <= 4 MB per-XCD L2 (round 7
//  thrashed: ~24 active bh x 512 KB ~ 12 MB/XCD -> FETCH 39 MB, WRITE 43 MB).

#define N_SEQ 2048
#define EMB   1024
#define NH    16
#define NKV   4
#define HD    64
#define BATCH 2
#define M_TOT 4096
#define QKV_N 1536

typedef __attribute__((ext_vector_type(8)))  short short8;   // 8 bf16
typedef __attribute__((ext_vector_type(4)))  float f32x4;
typedef __attribute__((ext_vector_type(16))) float f32x16;

__device__ __forceinline__ ushort f2bf(float f) {
    union { __hip_bfloat16 h; ushort u; } cv;
    cv.h = __float2bfloat16(f);
    return cv.u;
}
__device__ __forceinline__ float bf2f(ushort u) {
    union { __hip_bfloat16 h; ushort u; } cv;
    cv.u = u;
    return __bfloat162float(cv.h);
}
__device__ __forceinline__ uint pack2bf(float a, float b) {
    union { __hip_bfloat162 h; uint u; } cv;
    cv.h = __float22bfloat162_rn(float2{a, b});
    return cv.u;
}

// ---------------------------------------------------------------------------
// Fused prep (unchanged)
// ---------------------------------------------------------------------------
__device__ __forceinline__ void cvt4(const float* __restrict__ s,
                                     ushort* __restrict__ d, long g, long gd) {
    const float4 v = ((const float4*)s)[g];
    ushort4 o;
    o.x = f2bf(v.x); o.y = f2bf(v.y); o.z = f2bf(v.z); o.w = f2bf(v.w);
    ((ushort4*)d)[gd] = o;
}

__global__ __launch_bounds__(256) void prep_kernel(
    const float* __restrict__ x,  const float* __restrict__ wq,
    const float* __restrict__ wk, const float* __restrict__ wv,
    const float* __restrict__ wp, const float* __restrict__ bq,
    const float* __restrict__ bk, const float* __restrict__ bv,
    ushort* __restrict__ xb, ushort* __restrict__ Wqkv,
    ushort* __restrict__ Wproj, float* __restrict__ bqkv)
{
    const long i = (long)blockIdx.x * 256 + threadIdx.x;
    if (i < 1048576) {
        cvt4(x, xb, i, i);
    } else if (i < 1310720) {
        const long g = i - 1048576;
        cvt4(wq, Wqkv, g, g);
    } else if (i < 1376256) {
        const long g = i - 1310720;
        cvt4(wk, Wqkv, g, 262144 + g);
    } else if (i < 1441792) {
        const long g = i - 1376256;
        cvt4(wv, Wqkv, g, 327680 + g);
    } else if (i < 1703936) {
        const long g = i - 1441792;
        cvt4(wp, Wproj, g, g);
    } else if (i < 1704320) {
        const long j = i - 1703936;
        float4 v;
        if (j < 256)      v = ((const float4*)bq)[j];
        else if (j < 320) v = ((const float4*)bk)[j - 256];
        else              v = ((const float4*)bv)[j - 320];
        ((float4*)bqkv)[j] = v;
    }
}

// ---------------------------------------------------------------------------
// bf16 MFMA GEMM, 64(M)x128(N) tile, BK=32, 4 waves (wave = 32m x 64n).
// ---------------------------------------------------------------------------
template <bool BF16OUT>
__global__ __launch_bounds__(256) void gemm_mfma_kernel(
    const ushort* __restrict__ A, const ushort* __restrict__ W,
    const float* __restrict__ bias, void* __restrict__ Cout,
    int K, int ldc)
{
    __shared__ ushort As[64 * 40];
    __shared__ ushort Bs[128 * 40];

    const int tid = threadIdx.x;
    const int m0 = blockIdx.y * 64, n0 = blockIdx.x * 128;
    const int w = tid >> 6, lane = tid & 63;
    const int quad = lane >> 4, l16 = lane & 15;
    const int wm = (w & 1) * 32, wn = (w >> 1) * 64;

    f32x4 acc[2][4] = {};

    float bb[4];
#pragma unroll
    for (int j = 0; j < 4; ++j) bb[j] = bias[n0 + wn + j * 16 + l16];

    const int r0 = tid >> 2;
    const int c0 = tid & 3;
    const ushort* Ap = A + (size_t)(m0 + r0) * K + c0 * 8;
    const ushort* Wp = W + (size_t)(n0 + r0) * K + c0 * 8;

    for (int k0 = 0; k0 < K; k0 += 32) {
        const short8 a0 = *(const short8*)(Ap + k0);
        const short8 b0 = *(const short8*)(Wp + k0);
        const short8 b1 = *(const short8*)(Wp + (size_t)64 * K + k0);
        __syncthreads();
        *(short8*)&As[r0 * 40 + c0 * 8] = a0;
        *(short8*)&Bs[r0 * 40 + c0 * 8] = b0;
        *(short8*)&Bs[(r0 + 64) * 40 + c0 * 8] = b1;
        __syncthreads();

        short8 aF[2], bF[4];
#pragma unroll
        for (int i = 0; i < 2; ++i)
            aF[i] = *(const short8*)&As[(wm + i * 16 + l16) * 40 + quad * 8];
#pragma unroll
        for (int j = 0; j < 4; ++j)
            bF[j] = *(const short8*)&Bs[(wn + j * 16 + l16) * 40 + quad * 8];
#pragma unroll
        for (int i = 0; i < 2; ++i)
#pragma unroll
            for (int j = 0; j < 4; ++j)
                acc[i][j] = __builtin_amdgcn_mfma_f32_16x16x32_bf16(
                    aF[i], bF[j], acc[i][j], 0, 0, 0);
    }

#pragma unroll
    for (int i = 0; i < 2; ++i) {
        const int rowb = m0 + wm + i * 16 + quad * 4;
#pragma unroll
        for (int j = 0; j < 4; ++j) {
            const int col = n0 + wn + j * 16 + l16;
#pragma unroll
            for (int r = 0; r < 4; ++r) {
                const float vv = acc[i][j][r] + bb[j];
                if (BF16OUT)
                    ((ushort*)Cout)[(size_t)(rowb + r) * ldc + col] = f2bf(vv);
                else
                    ((float*)Cout)[(size_t)(rowb + r) * ldc + col] = vv;
            }
        }
    }
}

// ---------------------------------------------------------------------------
// Fused RMSNorm+RoPE (Q,K) + V transpose, one launch (unchanged).
// ---------------------------------------------------------------------------
__global__ __launch_bounds__(256) void norm_rope_tv_kernel(
    const ushort* __restrict__ Tq, const float* __restrict__ qn_w,
    const float* __restrict__ kn_w, const float* __restrict__ sinp,
    const float* __restrict__ cosp, ushort* __restrict__ Qb,
    ushort* __restrict__ Kf, ushort* __restrict__ Vf)
{
    __shared__ ushort L[64 * 72];
    const int tid = threadIdx.x;

    if (blockIdx.x < 20480) {
        const int gw = (int)(((long)blockIdx.x * 256 + tid) >> 6);
        const int lane = tid & 63;

        const bool isQ = (gw < 65536);
        const int vec = isQ ? gw : gw - 65536;
        const int hshift = isQ ? 4 : 2;
        const int colBase = isQ ? 0 : EMB;
        const float* nw = isQ ? qn_w : kn_w;
        const float outScale = isQ ? 0.125f * 1.44269504f : 1.0f;

        const int m = vec >> hshift;
        const int h = vec & ((1 << hshift) - 1);
        const int n = m & (N_SEQ - 1);
        const int b = m >> 11;

        const float t = bf2f(Tq[(size_t)m * QKV_N + colBase + h * HD + lane]);
        float s = t * t;
#pragma unroll
        for (int mask = 32; mask; mask >>= 1) s += __shfl_xor(s, mask, 64);
        const float r = rsqrtf(s * (1.0f / 64.0f) + 1e-6f);

        const float tn = t * r * nw[lane];
        const float partner = __shfl_xor(tn, 32, 64);
        const float rot = (lane < 32) ? -partner : partner;
        const float val = (tn * cosp[n * HD + lane] + rot * sinp[n * HD + lane]) * outScale;

        if (isQ) {
            Qb[((size_t)((b << 4) + h) * N_SEQ + n) * HD + lane] = f2bf(val);
        } else {
            const int kt = n >> 6, rr = n & 63, ss = rr >> 5, l32k = rr & 31;
            const int c = lane >> 4, l5k = (lane >> 3) & 1, j = lane & 7;
            Kf[((size_t)(b * NKV + h) * 32 + kt) * 4096
               + (ss * 4 + c) * 512 + l32k * 16 + l5k * 8 + j] = f2bf(val);
        }
        return;
    }

    // ---- V transpose path ----
    const int bid = blockIdx.x - 20480;    // 0..255
    const int kt = bid & 31;
    const int bkv = bid >> 5;
    const int n0 = kt * 64;
    const int b = bkv >> 2, kv = bkv & 3;

#pragma unroll
    for (int it = 0; it < 2; ++it) {
        const int j = tid + it * 256;
        const int r = j >> 3, c = j & 7;
        const short8 v = *(const short8*)&Tq[(size_t)(b * N_SEQ + n0 + r) * QKV_N
                                             + 1280 + kv * HD + c * 8];
        *(short8*)&L[r * 72 + c * 8] = v;
    }
    __syncthreads();
#pragma unroll
    for (int it = 0; it < 2; ++it) {
        const int j = tid + it * 256;
        const int d = j >> 3, c8 = j & 7;
        short8 o;
#pragma unroll
        for (int e = 0; e < 8; ++e) o[e] = (short)L[(c8 * 8 + e) * 72 + d];
        const int ss = c8 >> 2, tt = (c8 >> 1) & 1, l5v = c8 & 1;
        const int d2 = d >> 5, l32v = d & 31;
        *(short8*)&Vf[((size_t)bkv * 32 + kt) * 4096
                      + ((ss * 2 + tt) * 2 + d2) * 512 + l32v * 16 + l5v * 8] = o;
    }
}

// ---------------------------------------------------------------------------
// Barrier-free flash, fixed-max softmax, XCD-pinned grid.
// 1-D grid of 1024 blocks: xcd = blk&7, wi = blk>>3,
// bh = xcd + 8*(wi>>5), qt = wi&31. Each XCD sees only 4 bh -> K/V (2 MB)
// stays L2-resident; per-bh K/V fetched from HBM once.
// ---------------------------------------------------------------------------
__global__ __launch_bounds__(256, 4) void flash_mfma32_kernel(
    const ushort* __restrict__ Qb, const ushort* __restrict__ Kf,
    const ushort* __restrict__ Vf, ushort* __restrict__ Ob)
{
    __shared__ float fsm[4352];

    const int blk = blockIdx.x;
    const int xcd = blk & 7;
    const int wi = blk >> 3;
    const int bh = xcd + 8 * (wi >> 5);    // b*16+h
    const int qt = wi & 31;
    const int b = bh >> 4, h = bh & 15;
    const int kvh = h >> 2;
    const int tid = threadIdx.x;
    const int w = tid >> 6, lane = tid & 63;
    const int l32 = lane & 31, l5 = lane >> 5;
    const int qg = w & 1;
    const int kh = w >> 1;

    const ushort* Qg = Qb + ((size_t)bh * N_SEQ + qt * 64 + qg * 32) * HD;
    const size_t kvbase = (size_t)(b * NKV + kvh) * (32 * 4096);
    const ushort* Kp = Kf + kvbase + (size_t)kh * 16 * 4096;
    const ushort* Vp = Vf + kvbase + (size_t)kh * 16 * 4096;
    const int loff = l32 * 16 + l5 * 8;

    short8 qF[4];
#pragma unroll
    for (int c = 0; c < 4; ++c)
        qF[c] = *(const short8*)&Qg[(size_t)l32 * HD + c * 16 + l5 * 8];

    f32x16 Oa[2] = {};
    float lrow = 0.0f;

    short8 kN[2][4];
#pragma unroll
    for (int s = 0; s < 2; ++s)
#pragma unroll
        for (int c = 0; c < 4; ++c)
            kN[s][c] = *(const short8*)&Kp[(s * 4 + c) * 512 + loff];

    for (int i = 0; i < 16; ++i) {
        short8 kC[2][4];
#pragma unroll
        for (int s = 0; s < 2; ++s)
#pragma unroll
            for (int c = 0; c < 4; ++c) kC[s][c] = kN[s][c];

        const ushort* Vt = Vp + i * 4096;
        short8 vT[2][2][2];
#pragma unroll
        for (int s = 0; s < 2; ++s)
#pragma unroll
            for (int t = 0; t < 2; ++t)
#pragma unroll
                for (int d2 = 0; d2 < 2; ++d2)
                    vT[s][t][d2] = *(const short8*)&Vt[((s * 2 + t) * 2 + d2) * 512 + loff];

        if (i + 1 < 16) {
            const ushort* Kt = Kp + (i + 1) * 4096;
#pragma unroll
            for (int s = 0; s < 2; ++s)
#pragma unroll
                for (int c = 0; c < 4; ++c)
                    kN[s][c] = *(const short8*)&Kt[(s * 4 + c) * 512 + loff];
        }

        f32x16 Sv[2] = {};
#pragma unroll
        for (int s = 0; s < 2; ++s)
#pragma unroll
            for (int c = 0; c < 4; ++c)
                Sv[s] = __builtin_amdgcn_mfma_f32_32x32x16_bf16(kC[s][c], qF[c], Sv[s], 0, 0, 0);

        // P = exp2(S'); l += this lane's 32 key-entries
        float rs = 0.0f;
#pragma unroll
        for (int s = 0; s < 2; ++s)
#pragma unroll
            for (int r = 0; r < 16; ++r) {
                Sv[s][r] = __builtin_amdgcn_exp2f(Sv[s][r]);
                rs += Sv[s][r];
            }
        lrow += rs;

        uint P2[2][8];
#pragma unroll
        for (int s = 0; s < 2; ++s)
#pragma unroll
            for (int g = 0; g < 4; ++g)
#pragma unroll
                for (int hh = 0; hh < 2; ++hh)
                    P2[s][g * 2 + hh] =
                        pack2bf(Sv[s][4 * g + 2 * hh], Sv[s][4 * g + 2 * hh + 1]);

#pragma unroll
        for (int s = 0; s < 2; ++s)
#pragma unroll
            for (int t = 0; t < 2; ++t) {
                const uint snd0 = l5 ? P2[s][4 * t + 0] : P2[s][4 * t + 2];
                const uint snd1 = l5 ? P2[s][4 * t + 1] : P2[s][4 * t + 3];
                const uint kp0  = l5 ? P2[s][4 * t + 2] : P2[s][4 * t + 0];
                const uint kp1  = l5 ? P2[s][4 * t + 3] : P2[s][4 * t + 1];
                const uint rcv0 = __shfl_xor(snd0, 32, 64);
                const uint rcv1 = __shfl_xor(snd1, 32, 64);
                union { uint u[4]; short8 s8; } pb;
                pb.u[0] = l5 ? rcv0 : kp0;
                pb.u[1] = l5 ? rcv1 : kp1;
                pb.u[2] = l5 ? kp0 : rcv0;
                pb.u[3] = l5 ? kp1 : rcv1;
#pragma unroll
                for (int d2 = 0; d2 < 2; ++d2)
                    Oa[d2] = __builtin_amdgcn_mfma_f32_32x32x16_bf16(
                        vT[s][t][d2], pb.s8, Oa[d2], 0, 0, 0);
            }
    }

    // partner lane's key-half of the denominator
    lrow += __shfl_xor(lrow, 32, 64);

    // ---- merge k-halves: plain sums ----
    float* buf = fsm + qg * 2112;
    if (kh == 1) {
#pragma unroll
        for (int d2 = 0; d2 < 2; ++d2)
#pragma unroll
            for (int r = 0; r < 16; ++r)
                buf[(d2 * 16 + r) * 64 + lane] = Oa[d2][r];
        buf[2048 + lane] = lrow;
    }
    __syncthreads();

    if (kh == 0) {
        lrow += buf[2048 + lane];
#pragma unroll
        for (int d2 = 0; d2 < 2; ++d2)
#pragma unroll
            for (int r = 0; r < 16; ++r)
                Oa[d2][r] += buf[(d2 * 16 + r) * 64 + lane];
    }
    __syncthreads();

    // ---- epilogue: normalize + transpose via LDS, coalesced store ----
    ushort* Os = (ushort*)fsm;
    if (kh == 0) {
        const float inv = 1.0f / lrow;
#pragma unroll
        for (int d2 = 0; d2 < 2; ++d2)
#pragma unroll
            for (int r = 0; r < 16; ++r) {
                const int d = d2 * 32 + (r & 3) + 8 * (r >> 2) + 4 * l5;
                Os[(qg * 32 + l32) * 68 + d] = f2bf(Oa[d2][r] * inv);
            }
    }
    __syncthreads();

    const int row = tid >> 2, cc = (tid & 3) * 16;
#pragma unroll
    for (int i = 0; i < 2; ++i) {
        const short8 v = *(const short8*)&Os[row * 68 + cc + i * 8];
        *(short8*)&Ob[((size_t)b * N_SEQ + qt * 64 + row) * EMB + h * HD + cc + i * 8] = v;
    }
}

// ---------------------------------------------------------------------------
extern "C" void kernel_launch(void* const* d_in, const int* in_sizes, int n_in,
                              void* d_out, int out_size, void* d_ws, size_t ws_size,
                              hipStream_t stream)
{
    const float* x      = (const float*)d_in[0];
    const float* sinp   = (const float*)d_in[1];
    const float* cosp   = (const float*)d_in[2];
    const float* wq_w   = (const float*)d_in[3];
    const float* wq_b   = (const float*)d_in[4];
    const float* wk_w   = (const float*)d_in[5];
    const float* wk_b   = (const float*)d_in[6];
    const float* wv_w   = (const float*)d_in[7];
    const float* wv_b   = (const float*)d_in[8];
    const float* qn_w   = (const float*)d_in[9];
    const float* kn_w   = (const float*)d_in[10];
    const float* proj_w = (const float*)d_in[11];
    const float* proj_b = (const float*)d_in[12];
    float* out = (float*)d_out;

    // workspace layout (ushort elements) — ~39 MB
    ushort* Tq    = (ushort*)d_ws;            // 4096*1536
    ushort* xb    = Tq + 6291456;             // 4096*1024 (reused as Ob)
    ushort* Wqkv  = xb + 4194304;             // 1536*1024
    ushort* Wproj = Wqkv + 1572864;           // 1024*1024
    float*  bqkv  = (float*)(Wproj + 1048576);// 1536
    ushort* Qb    = (ushort*)(bqkv + 1536);   // 2*16*2048*64
    ushort* Kf    = Qb + 4194304;             // frag-order K
    ushort* Vf    = Kf + 1048576;             // frag-order V^T

    prep_kernel<<<6658, 256, 0, stream>>>(x, wq_w, wk_w, wv_w, proj_w,
                                          wq_b, wk_b, wv_b,
                                          xb, Wqkv, Wproj, bqkv);

    gemm_mfma_kernel<true><<<dim3(QKV_N / 128, M_TOT / 64), 256, 0, stream>>>(
        xb, Wqkv, bqkv, Tq, EMB, QKV_N);

    norm_rope_tv_kernel<<<20736, 256, 0, stream>>>(Tq, qn_w, kn_w, sinp, cosp,
                                                   Qb, Kf, Vf);

    flash_mfma32_kernel<<<1024, 256, 0, stream>>>(Qb, Kf, Vf, xb);

    gemm_mfma_kernel<false><<<dim3(EMB / 128, M_TOT / 64), 256, 0, stream>>>(
        xb, Wproj, proj_b, out, EMB, EMB);
}